// Round 1
// baseline (184.154 us; speedup 1.0000x reference)
//
#include <hip/hip_runtime.h>
#include <math.h>

#define NS    512
#define NOBJ  16
#define MPTS  8192
#define HH    128
#define WW    128
#define HW    (HH * WW)
#define BLOCK 512
#define NWAVE (BLOCK / 64)
#define WSPAN (HW / NWAVE)          // 2048 contiguous px per wave
#define GRP   256                   // px per dwordx4 wave-instruction
#define STG   2                     // insts per array per stage (2-KB runs)
#define NSTG  (WSPAN / (GRP * STG)) // 4 stages per wave
#define M_IT  (MPTS / 4 / BLOCK)    // 4 mesh groups per thread

typedef float f4 __attribute__((ext_vector_type(4)));
typedef int   i4 __attribute__((ext_vector_type(4)));

__device__ __forceinline__ float frcp(float x)  { return __builtin_amdgcn_rcpf(x); }
__device__ __forceinline__ float fsqrt(float x) { return __builtin_amdgcn_sqrtf(x); }
__device__ __forceinline__ float rfl(float x) {
    return __int_as_float(__builtin_amdgcn_readfirstlane(__float_as_int(x)));
}
__device__ __forceinline__ void sched_fence() {
#if __has_builtin(__builtin_amdgcn_sched_barrier)
    __builtin_amdgcn_sched_barrier(0);
#endif
}
__device__ __forceinline__ f4 ntl_f4(const f4* p) {
#if __has_builtin(__builtin_nontemporal_load)
    return __builtin_nontemporal_load(p);
#else
    return *p;
#endif
}
__device__ __forceinline__ i4 ntl_i4(const i4* p) {
#if __has_builtin(__builtin_nontemporal_load)
    return __builtin_nontemporal_load(p);
#else
    return *p;
#endif
}

__device__ __forceinline__ void fuse_proj(const float* __restrict__ cam_K,
                                          const float* __restrict__ R,
                                          const float* __restrict__ t, int n,
                                          float A[9], float b[3]) {
    float K[9], Rr[9], tt[3];
#pragma unroll
    for (int i = 0; i < 9; ++i) { K[i] = cam_K[n * 9 + i]; Rr[i] = R[n * 9 + i]; }
#pragma unroll
    for (int i = 0; i < 3; ++i) tt[i] = t[n * 3 + i];
#pragma unroll
    for (int r = 0; r < 3; ++r) {
#pragma unroll
        for (int c = 0; c < 3; ++c)
            A[r * 3 + c] = rfl(K[r * 3 + 0] * Rr[0 * 3 + c]
                             + K[r * 3 + 1] * Rr[1 * 3 + c]
                             + K[r * 3 + 2] * Rr[2 * 3 + c]);
        b[r] = rfl(K[r * 3 + 0] * tt[0] + K[r * 3 + 1] * tt[1] + K[r * 3 + 2] * tt[2]);
    }
}

// R0 change: per-block PHASE DE-CORRELATION of the load streams.
// Theory: every concurrent stream in the old mapping sat at a multiple of
// 8 KB from every other (cx/cy/cz 64 KB apart, waves 8 KB apart, blocks
// 192/64 KB apart) and all blocks run the identical stage schedule in
// lockstep -> instantaneous traffic concentrates on one phase-subset of the
// HBM channel interleave (period ~32 KB), capping reads at ~2.4 TB/s while
// the harness fill (one linear stream) hits 6.7 TB/s. Fix: permute the
// wave->span assignment by block (8-KB phase steps) and rotate the stage
// order per block group (2-KB phase steps) so the 512 blocks collectively
// cover every 2-KB phase. Burst shape, bytes, coalescing all unchanged.
__global__ __attribute__((amdgpu_flat_work_group_size(BLOCK, BLOCK),
                          amdgpu_waves_per_eu(4, 4)))
void score_kernel(
    const int*   __restrict__ obj_id,
    const float* __restrict__ cam_K,
    const float* __restrict__ gt_R,
    const float* __restrict__ gt_t,
    const float* __restrict__ pr_R,
    const float* __restrict__ pr_t,
    const float* __restrict__ coord,      // [N,3,H,W]
    const int*   __restrict__ mask,       // [N,1,H,W]
    const float* __restrict__ mesh,       // [NOBJ,M,3]
    const float* __restrict__ diam,
    float*       __restrict__ out)        // [5*N]
{
    const int n    = blockIdx.x;
    const int tid  = threadIdx.x;
    const int w    = tid >> 6;
    const int lane = tid & 63;

    // ---- constants -> SGPR ----
    float Ap[9], Ag[9], bp[3], bg[3], dR[9], dt[3];
    fuse_proj(cam_K, pr_R, pr_t, n, Ap, bp);
    fuse_proj(cam_K, gt_R, gt_t, n, Ag, bg);
#pragma unroll
    for (int i = 0; i < 9; ++i) dR[i] = rfl(pr_R[n * 9 + i] - gt_R[n * 9 + i]);
#pragma unroll
    for (int i = 0; i < 3; ++i) dt[i] = rfl(pr_t[n * 3 + i] - gt_t[n * 3 + i]);
    const int obj = __builtin_amdgcn_readfirstlane(obj_id[n]);

    const float* cx = coord + (size_t)n * 3 * HW;
    const float* cy = cx + HW;
    const float* cz = cx + 2 * HW;
    const int*   mk = mask + (size_t)n * HW;

    // Phase de-correlation: block-dependent span permutation (8-KB steps)
    // and stage rotation (2-KB steps).
    const int spanw = (w + n) & (NWAVE - 1);
    const int rot   = (n >> 3) & (NSTG - 1);
    const int wbase = spanw * WSPAN + 4 * lane;

    // ---- pixel phase: depth-2 slot rotation over 4 stages ----
    f4 X[2][STG], Y[2][STG], Z[2][STG];
    i4 Mq[2][STG];

#define LOAD_STAGE(s, b)                                                     \
    {                                                                        \
        const int st_ = ((s) + rot) & (NSTG - 1);                            \
        _Pragma("unroll")                                                    \
        for (int g = 0; g < STG; ++g) {                                      \
            const int p = wbase + st_ * (STG * GRP) + g * GRP;               \
            X[b][g]  = ntl_f4((const f4*)(cx + p));                          \
            Y[b][g]  = ntl_f4((const f4*)(cy + p));                          \
            Z[b][g]  = ntl_f4((const f4*)(cz + p));                          \
            Mq[b][g] = ntl_i4((const i4*)(mk + p));                          \
        }                                                                    \
    }

    LOAD_STAGE(0, 0)
    LOAD_STAGE(1, 1)
    sched_fence();

    float s_pv = 0.0f, s_m = 0.0f;
#pragma unroll
    for (int s = 0; s < NSTG; ++s) {
        const int b = s & 1;
#pragma unroll
        for (int g = 0; g < STG; ++g) {
            const float xs[4] = {X[b][g].x, X[b][g].y, X[b][g].z, X[b][g].w};
            const float ys[4] = {Y[b][g].x, Y[b][g].y, Y[b][g].z, Y[b][g].w};
            const float zs[4] = {Z[b][g].x, Z[b][g].y, Z[b][g].z, Z[b][g].w};
            const int   ms[4] = {Mq[b][g].x, Mq[b][g].y, Mq[b][g].z, Mq[b][g].w};
#pragma unroll
            for (int j = 0; j < 4; ++j) {
                const float x = xs[j], y = ys[j], z = zs[j];
                const float hpx = fmaf(Ap[0], x, fmaf(Ap[1], y, fmaf(Ap[2], z, bp[0])));
                const float hpy = fmaf(Ap[3], x, fmaf(Ap[4], y, fmaf(Ap[5], z, bp[1])));
                const float hpz = fmaf(Ap[6], x, fmaf(Ap[7], y, fmaf(Ap[8], z, bp[2])));
                const float hgx = fmaf(Ag[0], x, fmaf(Ag[1], y, fmaf(Ag[2], z, bg[0])));
                const float hgy = fmaf(Ag[3], x, fmaf(Ag[4], y, fmaf(Ag[5], z, bg[1])));
                const float hgz = fmaf(Ag[6], x, fmaf(Ag[7], y, fmaf(Ag[8], z, bg[2])));
                const float iwp = frcp(hpz), iwg = frcp(hgz);
                const float du = fmaf(hpx, iwp, -hgx * iwg);
                const float dv = fmaf(hpy, iwp, -hgy * iwg);
                const float d  = fsqrt(fmaf(du, du, dv * dv));
                const float fm = (ms[j] != 0) ? 1.0f : 0.0f;
                s_pv += d * fm;
                s_m  += fm;
            }
        }
        if (s + 2 < NSTG) {
            LOAD_STAGE(s + 2, b)      // refill freed slot; stream stays sequential
            sched_fence();
        }
    }

    // ---- mesh phase: batch issue, consume (L2/L3-warm) ----
    const f4* mp4 = (const f4*)(mesh + (size_t)obj * MPTS * 3);
    f4 MF[M_IT][3];
#pragma unroll
    for (int it = 0; it < M_IT; ++it) {
        const int k = it * BLOCK + tid;
        MF[it][0] = mp4[k * 3 + 0];
        MF[it][1] = mp4[k * 3 + 1];
        MF[it][2] = mp4[k * 3 + 2];
    }
    sched_fence();

    float s_ad = 0.0f, s_pj = 0.0f;
#pragma unroll
    for (int it = 0; it < M_IT; ++it) {
        const f4 f0 = MF[it][0], f1 = MF[it][1], f2 = MF[it][2];
        const float px[4] = {f0.x, f0.w, f1.z, f2.y};
        const float py[4] = {f0.y, f1.x, f1.w, f2.z};
        const float pz[4] = {f0.z, f1.y, f2.x, f2.w};
#pragma unroll
        for (int j = 0; j < 4; ++j) {
            const float x = px[j], y = py[j], z = pz[j];
            const float dx = fmaf(dR[0], x, fmaf(dR[1], y, fmaf(dR[2], z, dt[0])));
            const float dy = fmaf(dR[3], x, fmaf(dR[4], y, fmaf(dR[5], z, dt[1])));
            const float dz = fmaf(dR[6], x, fmaf(dR[7], y, fmaf(dR[8], z, dt[2])));
            s_ad += fsqrt(fmaf(dx, dx, fmaf(dy, dy, dz * dz)));
            const float hpx = fmaf(Ap[0], x, fmaf(Ap[1], y, fmaf(Ap[2], z, bp[0])));
            const float hpy = fmaf(Ap[3], x, fmaf(Ap[4], y, fmaf(Ap[5], z, bp[1])));
            const float hpz = fmaf(Ap[6], x, fmaf(Ap[7], y, fmaf(Ap[8], z, bp[2])));
            const float hgx = fmaf(Ag[0], x, fmaf(Ag[1], y, fmaf(Ag[2], z, bg[0])));
            const float hgy = fmaf(Ag[3], x, fmaf(Ag[4], y, fmaf(Ag[5], z, bg[1])));
            const float hgz = fmaf(Ag[6], x, fmaf(Ag[7], y, fmaf(Ag[8], z, bg[2])));
            const float iwp = frcp(hpz), iwg = frcp(hgz);
            const float du = fmaf(hpx, iwp, -hgx * iwg);
            const float dv = fmaf(hpy, iwp, -hgy * iwg);
            s_pj += fsqrt(fmaf(du, du, dv * dv));
        }
    }

    // ---- block reduction ----
    float vals[4] = {s_ad, s_pj, s_pv, s_m};
#pragma unroll
    for (int k = 0; k < 4; ++k)
#pragma unroll
        for (int off = 32; off > 0; off >>= 1)
            vals[k] += __shfl_down(vals[k], off, 64);

    __shared__ float red[4][NWAVE];
    if (lane == 0) {
#pragma unroll
        for (int k = 0; k < 4; ++k) red[k][spanw] = vals[k];   // span-ordered sum
    }
    __syncthreads();

    if (tid == 0) {
        float tot[4];
#pragma unroll
        for (int k = 0; k < 4; ++k) {
            float s = 0.0f;
#pragma unroll
            for (int wv = 0; wv < NWAVE; ++wv) s += red[k][wv];
            tot[k] = s;
        }
        float Rg9[9], Rp9[9];
#pragma unroll
        for (int i = 0; i < 9; ++i) { Rg9[i] = gt_R[n * 9 + i]; Rp9[i] = pr_R[n * 9 + i]; }
        float trace = 0.0f;
#pragma unroll
        for (int i = 0; i < 9; ++i) trace += Rp9[i] * Rg9[i];
        trace = fminf(fmaxf(trace, -1.0f), 3.0f);
        const float te = sqrtf(dt[0] * dt[0] + dt[1] * dt[1] + dt[2] * dt[2]) * 100.0f;

        out[0 * NS + n] = acosf((trace - 1.0f) * 0.5f) * (180.0f / 3.14159265358979323846f);
        out[1 * NS + n] = te;
        out[2 * NS + n] = tot[0] * (1.0f / MPTS) / diam[obj];
        out[3 * NS + n] = tot[1] * (1.0f / MPTS);
        out[4 * NS + n] = tot[2] / fmaxf(tot[3], 1.0f);
    }
}

extern "C" void kernel_launch(void* const* d_in, const int* in_sizes, int n_in,
                              void* d_out, int out_size, void* d_ws, size_t ws_size,
                              hipStream_t stream) {
    const int*   obj_id = (const int*)  d_in[0];
    const float* cam_K  = (const float*)d_in[1];
    const float* gt_R   = (const float*)d_in[2];
    const float* gt_t   = (const float*)d_in[3];
    const float* pr_R   = (const float*)d_in[4];
    const float* pr_t   = (const float*)d_in[5];
    const float* coord  = (const float*)d_in[6];
    const int*   mask   = (const int*)  d_in[7];
    const float* mesh   = (const float*)d_in[8];
    const float* diam   = (const float*)d_in[9];
    float* out = (float*)d_out;

    score_kernel<<<NS, BLOCK, 0, stream>>>(obj_id, cam_K, gt_R, gt_t, pr_R, pr_t,
                                           coord, mask, mesh, diam, out);
}